// Round 16
// baseline (24.373 us; speedup 1.0000x reference)
//
#include <hip/hip_runtime.h>
#include <math.h>

#define RES 2048
#define NB  256

typedef _Float16 f16;
typedef __fp16   fp16x2 __attribute__((ext_vector_type(2)));
typedef _Float16 f16x8 __attribute__((ext_vector_type(8)));
typedef float    f32x16 __attribute__((ext_vector_type(16)));

#define BM 128
#define BN 128
#define BK 16
#define NKT (NB / BK)      // 16 k-tiles
#define PL  (BM * BK)      // 2048 elements per plane

#define STEP (2.0f / 2047.0f)

__device__ __forceinline__ f16x8 neg8(f16x8 v) {
    union { f16x8 h; unsigned int u[4]; } x;
    x.h = v;
    #pragma unroll
    for (int i = 0; i < 4; ++i) x.u[i] ^= 0x80008000u;
    return x.h;
}

__device__ __forceinline__ unsigned int pk2(float lo, float hi) {
    union { fp16x2 h; unsigned int u; } x;
    x.h = __builtin_amdgcn_cvt_pkrtz(lo, hi);
    return x.u;
}

// XOR-swizzle within a [128][16] f16 plane (bijective; b128 frag reads
// conflict-free, u32 eval writes <=2-way).
__device__ __forceinline__ int swzE(int row, int k) {
    return (row * BK + k) ^ ((row & 7) << 3);
}

// ---------------------------------------------------------------------------
// Fused kernel, OCCUPANCY edition (R16).
// R13 counters: OccupancyPercent 21.9 (2 waves/SIMD), VALUBusy 59% -> 41%
// of cycles stalled. Same 128x128 tile / 256 blocks, but 1024 threads =
// 16 waves -> 4 waves/SIMD: double TLP, identical total eval+MFMA work.
//   - wave MFMA tile 32x32 (wm = wave>>2 -> M, wn = wave&3 -> N),
//     acc = Re+Im = 32 VGPR, 4 frag reads + 4 MFMA per k-tile.
//   - eval: thread covers ONE side x 2 beams x 2 rows (half of before).
// ---------------------------------------------------------------------------
__global__ __launch_bounds__(1024) void ewald_fused(
    const float* __restrict__ theta, const float* __restrict__ reA,
    const float* __restrict__ imA, const float* __restrict__ x0A,
    const float* __restrict__ y0A, const float* __restrict__ lsA,
    const float* __restrict__ X, const float* __restrict__ Y,
    float* __restrict__ out)
{
    __shared__ f16 smA[2][2][PL];   // [buf][Re/Im][swizzled row*16+k]
    __shared__ f16 smB[2][2][PL];
    __shared__ float4 sP0[NB];      // {kx, ky, px, py}
    __shared__ float4 sP1[NB];      // {re, im, 1/sigma^2, -}

    const int t    = threadIdx.x;
    const int lane = t & 63;
    const int wave = t >> 6;       // 0..15
    const int wm   = wave >> 2;    // 0..3 -> M offset 32
    const int wn   = wave & 3;     // 0..3 -> N offset 32
    const int la   = lane & 31;
    const int lg   = lane >> 5;

    // XCD-aware swizzle (256 blocks, 8 XCDs)
    const int flat = blockIdx.x;
    const int swz  = (flat & 7) * 32 + (flat >> 3);
    const int m0   = (swz >> 4) * BM;
    const int n0   = (swz & 15) * BN;

    // ---- prologue: per-beam packed params into LDS ----
    if (t < NB) {
        const int b = t;
        const float th = theta[b];
        const float s = __sinf(th), c = __cosf(th);
        const float sig = __expf(lsA[b]) + 0.001f;
        sP0[b] = make_float4(50.0f * c, 50.0f * s, x0A[b], y0A[b]);
        sP1[b] = make_float4(reA[b], imA[b], 1.0f / (sig * sig), 0.0f);
    }
    __syncthreads();

    // ---- eval decode: side (waves 0-7 = A, 8-15 = B), beam pair, rows ----
    const int side = t >> 9;          // wave-uniform
    const int u    = t & 511;
    const int bp   = u & 7;           // beams bp*2, bp*2+1 within k-tile
    const int grp  = u >> 3;          // 0..63 -> rows grp*2, grp*2+1
    const int row0 = grp * 2;
    const int kk2  = bp * 2;

    const float c0 = -1.0f + (float)((side ? n0 : m0) + row0) * STEP;
    const float c1 = c0 + STEP;

    f16* const evBase = side ? &smB[0][0][0] : &smA[0][0][0];
    const int e0 = swzE(row0, kk2);
    const int e1 = swzE(row0 + 1, kk2);

    #define EVAL(bf, kt)                                                      \
    do {                                                                      \
        const int b0_ = (kt) * BK + kk2;                                      \
        float vR[2][2], vI[2][2];  /* [beam][row] */                          \
        _Pragma("unroll")                                                     \
        for (int jb = 0; jb < 2; ++jb) {                                      \
            const float4 p0 = sP0[b0_ + jb];                                  \
            const float4 p1 = sP1[b0_ + jb];                                  \
            const float k_ = side ? p0.y : p0.x;                              \
            const float p_ = side ? p0.w : p0.z;                              \
            _Pragma("unroll")                                                 \
            for (int r = 0; r < 2; ++r) {                                     \
                const float cv = r ? c1 : c0;                                 \
                const float ph = k_ * cv;                                     \
                const float sn = __sinf(ph), cs = __cosf(ph);                 \
                const float d_ = cv - p_;                                     \
                const float e_ = __expf(-d_ * d_ * p1.z);                     \
                if (side) { vR[jb][r] = e_ * cs; vI[jb][r] = e_ * sn; }       \
                else {                                                        \
                    vR[jb][r] = e_ * (p1.x * cs - p1.y * sn);                 \
                    vI[jb][r] = e_ * (p1.x * sn + p1.y * cs);                 \
                }                                                             \
            }                                                                 \
        }                                                                     \
        const int eb = (bf) * 2 * PL;                                         \
        _Pragma("unroll")                                                     \
        for (int r = 0; r < 2; ++r) {                                         \
            const int ee = (r ? e1 : e0) + eb;                                \
            *(unsigned int*)&evBase[ee]      = pk2(vR[0][r], vR[1][r]);       \
            *(unsigned int*)&evBase[ee + PL] = pk2(vI[0][r], vI[1][r]);       \
        }                                                                     \
    } while (0)

    // ---- fragment LDS element-offsets (swizzled, within a plane) ----
    const int offA = swzE(wm * 32 + la, lg * 8);
    const int offB = swzE(wn * 32 + la, lg * 8);

    f32x16 accRe = (f32x16)0.0f, accIm = (f32x16)0.0f;

    // ---- k-tile 0 ----
    EVAL(0, 0);
    __syncthreads();

    for (int kt = 0; kt < NKT; ++kt) {
        const int cur = kt & 1;
        const int cb  = cur * 2 * PL;
        const f16x8 aR = *(const f16x8*)&(&smA[0][0][0])[cb + offA];
        const f16x8 aI = *(const f16x8*)&(&smA[0][0][0])[cb + PL + offA];
        const f16x8 bR = *(const f16x8*)&(&smB[0][0][0])[cb + offB];
        const f16x8 bI = *(const f16x8*)&(&smB[0][0][0])[cb + PL + offB];
        const f16x8 bN = neg8(bI);

        __builtin_amdgcn_s_setprio(1);
        accRe = __builtin_amdgcn_mfma_f32_32x32x16_f16(aR, bR, accRe, 0, 0, 0);
        accIm = __builtin_amdgcn_mfma_f32_32x32x16_f16(aR, bI, accIm, 0, 0, 0);
        accRe = __builtin_amdgcn_mfma_f32_32x32x16_f16(aI, bN, accRe, 0, 0, 0);
        accIm = __builtin_amdgcn_mfma_f32_32x32x16_f16(aI, bR, accIm, 0, 0, 0);
        __builtin_amdgcn_s_setprio(0);

        // eval next k-tile into the other buffer (all waves passed the
        // previous barrier, so it is free)
        if (kt + 1 < NKT)
            EVAL(cur ^ 1, kt + 1);

        __syncthreads();
    }

    // ---- epilogue: out = Re^2 + Im^2 ----
    // C/D layout (32x32): col = lane&31, row = (reg&3) + 8*(reg>>2) + 4*(lane>>5)
    const int gn     = n0 + wn * 32 + la;
    const int gmBase = m0 + wm * 32;
    #pragma unroll
    for (int r = 0; r < 16; ++r) {
        const int row = (r & 3) + 8 * (r >> 2) + 4 * lg;
        const float er = accRe[r], ei = accIm[r];
        out[(size_t)(gmBase + row) * RES + gn] = er * er + ei * ei;
    }
    #undef EVAL
}

// ---------------------------------------------------------------------------
extern "C" void kernel_launch(void* const* d_in, const int* in_sizes, int n_in,
                              void* d_out, int out_size, void* d_ws, size_t ws_size,
                              hipStream_t stream) {
    const float* theta = (const float*)d_in[0];
    const float* reA   = (const float*)d_in[1];
    const float* imA   = (const float*)d_in[2];
    const float* x0A   = (const float*)d_in[3];
    const float* y0A   = (const float*)d_in[4];
    const float* lsA   = (const float*)d_in[5];
    const float* X     = (const float*)d_in[6];
    const float* Y     = (const float*)d_in[7];
    float* out = (float*)d_out;

    ewald_fused<<<256, 1024, 0, stream>>>(theta, reA, imA, x0A, y0A, lsA,
                                          X, Y, out);
}

// Round 17
// 22.065 us; speedup vs baseline: 1.1046x; 1.1046x over previous
//
#include <hip/hip_runtime.h>
#include <math.h>

#define RES 2048
#define NB  256
#define PLANE (RES * NB)       // 524288 f16 per plane (1 MB)
#define STEP (2.0f / 2047.0f)

typedef _Float16 f16;
typedef _Float16 f16x8 __attribute__((ext_vector_type(8)));
typedef float    f32x16 __attribute__((ext_vector_type(16)));

#define AS1 __attribute__((address_space(1)))
#define AS3 __attribute__((address_space(3)))

__device__ __forceinline__ void g2l16(const void* g, void* l) {
    // async 16B/lane global->LDS; LDS dest = wave-uniform base + lane*16
    __builtin_amdgcn_global_load_lds((const AS1 void*)g, (AS3 void*)l, 16, 0, 0);
}

__device__ __forceinline__ f16x8 neg8(f16x8 v) {
    union { f16x8 h; unsigned int u[4]; } x;
    x.h = v;
    #pragma unroll
    for (int i = 0; i < 4; ++i) x.u[i] ^= 0x80008000u;
    return x.h;
}

// ---------------------------------------------------------------------------
// Fragment-ordered table layout (verified passing in R15):
//   value(row, b) at  e = chunk*512 + (lane>>5)*256 + (row&31)*8 + (b&7)
//   chunk = (row>>5)*16 + kt  (kt = b>>4).  A wave's (row_blk, kt) fragment
//   is the contiguous 1 KB at plane + chunk*512 + lane*8 — MFMA lane order.
// ---------------------------------------------------------------------------

// Kernel 1: build 4 planes {aRe, aIm(coeff folded), bRe, bIm} in d_ws.
// Per-beam params staged in LDS once per block (-33% trans vs R15).
__global__ __launch_bounds__(256) void tables_frag(
    const float* __restrict__ theta, const float* __restrict__ reA,
    const float* __restrict__ imA, const float* __restrict__ x0A,
    const float* __restrict__ y0A, const float* __restrict__ lsA,
    f16* __restrict__ ws)
{
    __shared__ float4 sP0[NB];   // {kx, ky, px, py}
    __shared__ float4 sP1[NB];   // {re, im, is2, -}

    const int t = threadIdx.x;
    {
        const int b = t;
        const float th = theta[b];
        const float s = __sinf(th), c = __cosf(th);
        const float sig = __expf(lsA[b]) + 0.001f;
        sP0[b] = make_float4(50.0f * c, 50.0f * s, x0A[b], y0A[b]);
        sP1[b] = make_float4(reA[b], imA[b], 1.0f / (sig * sig), 0.0f);
    }
    __syncthreads();

    f16* aRe = ws;
    f16* aIm = ws + PLANE;
    f16* bRe = ws + 2 * PLANE;
    f16* bIm = ws + 3 * PLANE;

    const int gid = blockIdx.x * 256 + t;
    const int l   = gid & 63;
    const int w   = gid >> 6;              // chunk id 0..1023
    const int grow = (w >> 4) * 32 + (l & 31);
    const int b0   = (w & 15) * 16 + (l >> 5) * 8;
    const int e    = w * 512 + (l >> 5) * 256 + (l & 31) * 8;

    const float xv = -1.0f + (float)grow * STEP;  // x_i == y_j value

    float aRv[8], aIv[8], bRv[8], bIv[8];
    #pragma unroll
    for (int j = 0; j < 8; ++j) {
        const int b = b0 + j;
        const float4 p0 = sP0[b];
        const float4 p1 = sP1[b];

        const float phx = p0.x * xv;
        const float snx = __sinf(phx), csx = __cosf(phx);
        const float dx = xv - p0.z;
        const float ex = __expf(-dx * dx * p1.z);
        aRv[j] = ex * (p1.x * csx - p1.y * snx);
        aIv[j] = ex * (p1.x * snx + p1.y * csx);

        const float phy = p0.y * xv;
        const float sny = __sinf(phy), csy = __cosf(phy);
        const float dy = xv - p0.w;
        const float ey = __expf(-dy * dy * p1.z);
        bRv[j] = ey * csy;
        bIv[j] = ey * sny;
    }

    union { f16 h[8]; float4 v; } p;
    #pragma unroll
    for (int j = 0; j < 8; ++j) p.h[j] = (f16)aRv[j];
    *(float4*)&aRe[e] = p.v;
    #pragma unroll
    for (int j = 0; j < 8; ++j) p.h[j] = (f16)aIv[j];
    *(float4*)&aIm[e] = p.v;
    #pragma unroll
    for (int j = 0; j < 8; ++j) p.h[j] = (f16)bRv[j];
    *(float4*)&bRe[e] = p.v;
    #pragma unroll
    for (int j = 0; j < 8; ++j) p.h[j] = (f16)bIv[j];
    *(float4*)&bIm[e] = p.v;
}

// ---------------------------------------------------------------------------
// Kernel 2: complex GEMM. 64x128 output tile, 512 blocks = 2 blocks/CU
// (independent barriers -> vmcnt drains of one block hide under the other).
// Per k-tile: stage 12 frag-ordered chunks (1 KB each) global->LDS with
// global_load_lds (linear dest, zero staging VGPRs), then 4 waves each do
// 6 conflict-free b128 frag reads (lane-stride 16B) + 8 MFMA. One barrier
// per k-tile. L2 traffic ~100 MB total vs R15's ~196 MB, eval count 1x.
// ---------------------------------------------------------------------------
__global__ __launch_bounds__(256) void gemm_lds(
    const f16* __restrict__ ws, float* __restrict__ out)
{
    __shared__ f16 lds[2][12 * 512];   // [buf][12 chunks]

    const int t    = threadIdx.x;
    const int lane = t & 63;
    const int wave = t >> 6;       // 0..3 = wn (N sub-tile)
    const int la   = lane & 31;
    const int lg   = lane >> 5;

    // XCD-aware swizzle: 512 blocks, 8 XCDs, 64 contiguous per XCD
    const int flat = blockIdx.x;
    const int swz  = (flat & 7) * 64 + (flat >> 3);
    const int mb   = swz >> 4;     // 0..31
    const int nb   = swz & 15;     // 0..15
    const int m0   = mb * 64;
    const int n0   = nb * 128;

    // ---- staging map: 12 chunks/k-tile, 3 per wave ----
    // idx 0-1: aRe s=idx | 2-3: aIm s=idx-2 | 4-7: bRe s=idx-4 | 8-11: bIm
    const f16* gsrc[3];
    int ldst[3];
    #pragma unroll
    for (int j = 0; j < 3; ++j) {
        const int idx = wave + 4 * j;
        int p, rb;
        if (idx < 2)      { p = 0; rb = (m0 >> 5) + idx; }
        else if (idx < 4) { p = 1; rb = (m0 >> 5) + (idx - 2); }
        else if (idx < 8) { p = 2; rb = (n0 >> 5) + (idx - 4); }
        else              { p = 3; rb = (n0 >> 5) + (idx - 8); }
        gsrc[j] = ws + (size_t)p * PLANE + rb * 16 * 512 + lane * 8;
        ldst[j] = idx * 512;
    }

    #define STAGE(bf, kt)                                                     \
    do {                                                                      \
        g2l16(gsrc[0] + (kt) * 512, &lds[bf][ldst[0]]);                       \
        g2l16(gsrc[1] + (kt) * 512, &lds[bf][ldst[1]]);                       \
        g2l16(gsrc[2] + (kt) * 512, &lds[bf][ldst[2]]);                       \
    } while (0)

    // ---- fragment LDS offsets (within a buffer) ----
    const int lo   = lane * 8;
    const int oAR0 = 0 * 512 + lo, oAR1 = 1 * 512 + lo;
    const int oAI0 = 2 * 512 + lo, oAI1 = 3 * 512 + lo;
    const int oBR  = (4 + wave) * 512 + lo;
    const int oBI  = (8 + wave) * 512 + lo;

    f32x16 accRe0 = (f32x16)0.0f, accIm0 = (f32x16)0.0f;
    f32x16 accRe1 = (f32x16)0.0f, accIm1 = (f32x16)0.0f;

    STAGE(0, 0);
    __syncthreads();

    for (int kt = 0; kt < 16; ++kt) {
        const int cur = kt & 1;
        if (kt + 1 < 16)
            STAGE(cur ^ 1, kt + 1);

        const f16* s = lds[cur];
        const f16x8 aR0 = *(const f16x8*)(s + oAR0);
        const f16x8 aR1 = *(const f16x8*)(s + oAR1);
        const f16x8 aI0 = *(const f16x8*)(s + oAI0);
        const f16x8 aI1 = *(const f16x8*)(s + oAI1);
        const f16x8 bR  = *(const f16x8*)(s + oBR);
        const f16x8 bI  = *(const f16x8*)(s + oBI);
        const f16x8 bN  = neg8(bI);

        __builtin_amdgcn_s_setprio(1);
        accRe0 = __builtin_amdgcn_mfma_f32_32x32x16_f16(aR0, bR, accRe0, 0, 0, 0);
        accIm0 = __builtin_amdgcn_mfma_f32_32x32x16_f16(aR0, bI, accIm0, 0, 0, 0);
        accRe1 = __builtin_amdgcn_mfma_f32_32x32x16_f16(aR1, bR, accRe1, 0, 0, 0);
        accIm1 = __builtin_amdgcn_mfma_f32_32x32x16_f16(aR1, bI, accIm1, 0, 0, 0);
        accRe0 = __builtin_amdgcn_mfma_f32_32x32x16_f16(aI0, bN, accRe0, 0, 0, 0);
        accIm0 = __builtin_amdgcn_mfma_f32_32x32x16_f16(aI0, bR, accIm0, 0, 0, 0);
        accRe1 = __builtin_amdgcn_mfma_f32_32x32x16_f16(aI1, bN, accRe1, 0, 0, 0);
        accIm1 = __builtin_amdgcn_mfma_f32_32x32x16_f16(aI1, bR, accIm1, 0, 0, 0);
        __builtin_amdgcn_s_setprio(0);

        __syncthreads();   // next tile resident (vmcnt drained) + reads done
    }

    // ---- epilogue: out = Re^2 + Im^2 ----
    // C/D layout (32x32): col = lane&31, row = (reg&3) + 8*(reg>>2) + 4*(lane>>5)
    const int gn = n0 + wave * 32 + la;
    #pragma unroll
    for (int r = 0; r < 16; ++r) {
        const int row = (r & 3) + 8 * (r >> 2) + 4 * lg;
        const float er = accRe0[r], ei = accIm0[r];
        out[(size_t)(m0 + row) * RES + gn] = er * er + ei * ei;
    }
    #pragma unroll
    for (int r = 0; r < 16; ++r) {
        const int row = (r & 3) + 8 * (r >> 2) + 4 * lg;
        const float er = accRe1[r], ei = accIm1[r];
        out[(size_t)(m0 + 32 + row) * RES + gn] = er * er + ei * ei;
    }
    #undef STAGE
}

// ---------------------------------------------------------------------------
// Fallback: direct brute force (only if ws_size too small).
// ---------------------------------------------------------------------------
__global__ __launch_bounds__(256) void ewald_direct(
    const float* __restrict__ theta, const float* __restrict__ reA,
    const float* __restrict__ imA, const float* __restrict__ x0A,
    const float* __restrict__ y0A, const float* __restrict__ lsA,
    const float* __restrict__ X, const float* __restrict__ Y,
    float* __restrict__ out)
{
    __shared__ float kxs[NB], kys[NB], res[NB], ims[NB], pxs[NB], pys[NB], is2s[NB];
    const int t = threadIdx.x;
    if (t < NB) {
        const float th  = theta[t];
        const float sig = __expf(lsA[t]) + 0.001f;
        kxs[t] = 50.0f * __cosf(th);
        kys[t] = 50.0f * __sinf(th);
        res[t] = reA[t]; ims[t] = imA[t];
        pxs[t] = x0A[t]; pys[t] = y0A[t];
        is2s[t] = 1.0f / (sig * sig);
    }
    __syncthreads();
    const size_t npix = (size_t)RES * RES;
    for (size_t idx = (size_t)blockIdx.x * blockDim.x + t; idx < npix;
         idx += (size_t)gridDim.x * blockDim.x) {
        const float xv = X[idx], yv = Y[idx];
        float er = 0.f, ei = 0.f;
        for (int b = 0; b < NB; ++b) {
            const float dx = xv - pxs[b], dy = yv - pys[b];
            const float env = __expf(-(dx * dx + dy * dy) * is2s[b]);
            const float ph = kxs[b] * xv + kys[b] * yv;
            float s, c;
            __sincosf(ph, &s, &c);
            er += env * (res[b] * c - ims[b] * s);
            ei += env * (res[b] * s + ims[b] * c);
        }
        out[idx] = er * er + ei * ei;
    }
}

// ---------------------------------------------------------------------------
extern "C" void kernel_launch(void* const* d_in, const int* in_sizes, int n_in,
                              void* d_out, int out_size, void* d_ws, size_t ws_size,
                              hipStream_t stream) {
    const float* theta = (const float*)d_in[0];
    const float* reA   = (const float*)d_in[1];
    const float* imA   = (const float*)d_in[2];
    const float* x0A   = (const float*)d_in[3];
    const float* y0A   = (const float*)d_in[4];
    const float* lsA   = (const float*)d_in[5];
    const float* X     = (const float*)d_in[6];
    const float* Y     = (const float*)d_in[7];
    float* out = (float*)d_out;

    const size_t need = 4 * (size_t)PLANE * sizeof(f16);   // 4 MB

    if (ws_size >= need) {
        f16* ws = (f16*)d_ws;
        tables_frag<<<256, 256, 0, stream>>>(theta, reA, imA, x0A, y0A, lsA, ws);
        gemm_lds<<<512, 256, 0, stream>>>(ws, out);
    } else {
        ewald_direct<<<2048, 256, 0, stream>>>(theta, reA, imA, x0A, y0A, lsA,
                                               X, Y, out);
    }
}